// Round 8
// baseline (405.063 us; speedup 1.0000x reference)
//
#include <hip/hip_runtime.h>
#include <hip/hip_bf16.h>
#include <math.h>

// Problem constants (S=1024, B=2 -> T=2048)
#define T_  2048
#define H_  1024
#define F_  4096
#define E_  4
#define EF_ (E_*F_)
#define ROWCAP 4608   // sum_e ceil(cnt_e/128)*128 <= 4096 + 4*127 = 4604
#define KSPLIT 4      // gemm2 split-K slices
#define KS (F_/KSPLIT)

typedef __attribute__((ext_vector_type(8))) short short8;   // 8 bf16 = 4 VGPRs
typedef __attribute__((ext_vector_type(4))) float f32x4;    // MFMA 16x16 accumulator

#define BM 128
#define BN 128
#define BK 64

__device__ __forceinline__ void async_copy16(const void* g, void* l) {
    __builtin_amdgcn_global_load_lds(
        (const __attribute__((address_space(1))) void*)g,
        (__attribute__((address_space(3))) void*)l, 16, 0, 0);
}

__device__ __forceinline__ float bf2f(unsigned short u) {
    return __uint_as_float(((unsigned)u) << 16);
}
__device__ __forceinline__ short f2bf_bits(float f) {
    __hip_bfloat16 b = __float2bfloat16(f);
    return *(short*)&b;
}

// ONE prep kernel, grid (64,16,9):
//   z<4 : W1 expert z   [H][F] fp32 -> w1t[e][f][h] bf16 (64x64 LDS transpose)
//   4<=z<8 : W2 expert z-4 [F][H] fp32 -> w2t[h][e*F+f] bf16
//   z==8: X copy-convert fp32->bf16; block (0,0,8) also builds routing lists.
__global__ __launch_bounds__(256)
void trans_kernel(const float* __restrict__ w1, const float* __restrict__ w2,
                  const float* __restrict__ x,  const float* __restrict__ probs,
                  __hip_bfloat16* __restrict__ w1t, __hip_bfloat16* __restrict__ w2t,
                  __hip_bfloat16* __restrict__ xb,
                  int* __restrict__ cnt_g, int* __restrict__ off_g,
                  int* __restrict__ list, int* __restrict__ slot) {
    const int z = blockIdx.z;
    const int t = threadIdx.x;

    if (z == 2 * E_) {
        // ---- X convert path ----
        const int bid = blockIdx.y * 64 + blockIdx.x;          // 0..1023
        const size_t base = ((size_t)bid * 256 + t) * 8;       // 8 elems/thread
        const float4 v0 = *(const float4*)&x[base];
        const float4 v1 = *(const float4*)&x[base + 4];
        short8 pk;
        pk[0] = f2bf_bits(v0.x); pk[1] = f2bf_bits(v0.y);
        pk[2] = f2bf_bits(v0.z); pk[3] = f2bf_bits(v0.w);
        pk[4] = f2bf_bits(v1.x); pk[5] = f2bf_bits(v1.y);
        pk[6] = f2bf_bits(v1.z); pk[7] = f2bf_bits(v1.w);
        *(short8*)&((short*)xb)[base] = pk;

        // ---- routing (single designated block) ----
        if (blockIdx.x == 0 && blockIdx.y == 0) {
            __shared__ int lcnt[E_];
            if (t < E_) lcnt[t] = 0;
            __syncthreads();
            const int lane = t & 63;
            const unsigned long long below = ((lane == 63) ? ~0ull : ((1ull << (lane + 1)) - 1)) >> 1;
#pragma unroll
            for (int i = 0; i < T_ / 256; i++) {
                const int tok = i * 256 + t;
                const float4 p = *(const float4*)&probs[(size_t)tok * E_];
                const float pv[4] = {p.x, p.y, p.z, p.w};
#pragma unroll
                for (int e = 0; e < E_; e++) {
                    const bool r = pv[e] > 0.0f;
                    const unsigned long long mask = __ballot(r);
                    int base_pos = 0;
                    if (lane == 0) base_pos = atomicAdd(&lcnt[e], __popcll(mask));
                    base_pos = __shfl(base_pos, 0);
                    const int pos = base_pos + (int)__popcll(mask & below);
                    if (r) { list[e * T_ + pos] = tok; slot[tok * E_ + e] = pos; }
                }
            }
            __syncthreads();
            if (t == 0) {
                int acc = 0;
#pragma unroll
                for (int e = 0; e < E_; e++) {
                    off_g[e] = acc; cnt_g[e] = lcnt[e];
                    acc += (lcnt[e] + 127) & ~127;
                }
                off_g[E_] = acc;
            }
        }
        return;
    }

    // ---- weight transpose paths (verified R6) ----
    __shared__ float tile[64 * 69 + 4];   // tile[c][r] at c*69 + r
    const float* src;
    __hip_bfloat16* dst;
    int r0, c0, C, dstStride;
    if (z < E_) {
        src = w1 + (size_t)z * H_ * F_;
        dst = w1t + (size_t)z * F_ * H_;
        C = F_; dstStride = H_;
        r0 = blockIdx.y * 64;   // over H
        c0 = blockIdx.x * 64;   // over F
    } else {
        const int e = z - E_;
        src = w2 + (size_t)e * F_ * H_;
        dst = w2t + (size_t)e * F_;     // element (r=f,c=h) -> dst[c*EF_ + r]
        C = H_; dstStride = EF_;
        r0 = blockIdx.x * 64;   // over F
        c0 = blockIdx.y * 64;   // over H
    }
    const int cl = (t & 15) * 4;
#pragma unroll
    for (int p = 0; p < 4; p++) {
        const int rl = (t >> 4) + 16 * p;
        const float4 v = *(const float4*)&src[(size_t)(r0 + rl) * C + (c0 + cl)];
        tile[(cl + 0) * 69 + rl] = v.x;
        tile[(cl + 1) * 69 + rl] = v.y;
        tile[(cl + 2) * 69 + rl] = v.z;
        tile[(cl + 3) * 69 + rl] = v.w;
    }
    __syncthreads();
    const int orow = (t & 7) * 8;
#pragma unroll
    for (int q = 0; q < 2; q++) {
        const int oc = (t >> 3) + 32 * q;
        short8 pk;
#pragma unroll
        for (int j = 0; j < 8; j++)
            pk[j] = f2bf_bits(tile[oc * 69 + orow + j]);
        *(short8*)&((short*)dst)[(size_t)(c0 + oc) * dstStride + r0 + orow] = pk;
    }
}

// LDS swizzle (B-tile only): row r chunk c stored at c ^ (r&7); staging fetches the
// permuted global chunk per lane; readers XOR. Conflict-free (verified R2).
// A-operand: DIRECT global->VGPR short8 fragment loads (A[m=lane&15][k=(lane>>4)*8+j]);
// halves the global_load_lds barrier-drain volume and the ds_read load. LDS 16KB/block.

// GEMM1 (gathered): Ag[off[e]+i][f] = bf16( p * gelu( (X[list[e][i]] @ W1_e)[f] ) )
__global__ __launch_bounds__(256, 4)
void gemm1_kernel(const __hip_bfloat16* __restrict__ Xb,
                  const __hip_bfloat16* __restrict__ W1t,
                  const float* __restrict__ probs,
                  const int* __restrict__ cnt, const int* __restrict__ off,
                  const int* __restrict__ list,
                  __hip_bfloat16* __restrict__ Ag) {
    const int e  = blockIdx.z;
    const int ce = cnt[e];
    const int m0 = blockIdx.y * BM;
    if (m0 >= ce) return;
    const int n0 = blockIdx.x * BN;   // over F
    const __hip_bfloat16* Bt = W1t + (size_t)e * F_ * H_;
    __shared__ __align__(16) __hip_bfloat16 Bs[BN * BK];
    const int tid = threadIdx.x, lane = tid & 63, wave = tid >> 6;
    const int wm = (wave >> 1) * 64, wn = (wave & 1) * 64;
    const int lr  = lane >> 3;
    const int lcg = ((lane & 7) ^ lr) * 8;
    const int mr  = lane & 15;
    const int kq8 = (lane >> 4) * 8;

    // per-lane A-row base pointers (token-gathered)
    const __hip_bfloat16* aRow[4];
#pragma unroll
    for (int mi = 0; mi < 4; mi++) {
        int ci = m0 + wm + mi * 16 + mr;
        if (ci >= ce) ci = ce - 1;
        aRow[mi] = Xb + (size_t)list[e * T_ + ci] * H_;
    }

    f32x4 acc[4][4];
#pragma unroll
    for (int mi = 0; mi < 4; mi++)
#pragma unroll
        for (int ni = 0; ni < 4; ni++) acc[mi][ni] = (f32x4){0.f, 0.f, 0.f, 0.f};

    for (int k0 = 0; k0 < H_; k0 += BK) {
#pragma unroll
        for (int j = 0; j < 4; j++) {
            const int i = wave * 4 + j;
            async_copy16(Bt + (size_t)(n0 + i * 8 + lr) * H_ + (k0 + lcg),
                         (char*)Bs + i * 1024);
        }
        short8 a0[4], a1[4];
#pragma unroll
        for (int mi = 0; mi < 4; mi++) a0[mi] = *(const short8*)&aRow[mi][k0 + kq8];
#pragma unroll
        for (int mi = 0; mi < 4; mi++) a1[mi] = *(const short8*)&aRow[mi][k0 + 32 + kq8];
        __syncthreads();
#pragma unroll
        for (int kt = 0; kt < 2; kt++) {
            const int kq = kt * 4 + (lane >> 4);
            const int sw = mr & 7;
            short8 bF[4];
#pragma unroll
            for (int ni = 0; ni < 4; ni++)
                bF[ni] = *(const short8*)&Bs[(wn + ni * 16 + mr) * BK + ((kq ^ sw) << 3)];
#pragma unroll
            for (int mi = 0; mi < 4; mi++)
#pragma unroll
                for (int ni = 0; ni < 4; ni++)
                    acc[mi][ni] = __builtin_amdgcn_mfma_f32_16x16x32_bf16(
                        kt ? a1[mi] : a0[mi], bF[ni], acc[mi][ni], 0, 0, 0);
        }
        __syncthreads();
    }
    // C/D: col = lane&15, row = (lane>>4)*4 + reg
    const int rq = (lane >> 4) * 4, cq = lane & 15;
    const int obase = off[e] + m0;
#pragma unroll
    for (int mi = 0; mi < 4; mi++) {
#pragma unroll
        for (int reg = 0; reg < 4; reg++) {
            const int rl = wm + mi * 16 + rq + reg;
            int ci = m0 + rl; if (ci >= ce) ci = ce - 1;
            const int tok = list[e * T_ + ci];
            const float pv = probs[(size_t)tok * E_ + e];
#pragma unroll
            for (int ni = 0; ni < 4; ni++) {
                const int col = n0 + wn + ni * 16 + cq;
                const float v = acc[mi][ni][reg];
                // tanh-gelu via sigmoid: 0.5(1+tanh(u)) = sigma(2u); dev vs erf-gelu ~3e-3
                const float u = 0.7978845608028654f * v * (1.0f + 0.044715f * v * v);
                const float g = v / (1.0f + __expf(-2.0f * u));
                Ag[(size_t)(obase + rl) * F_ + col] = __float2bfloat16(g * pv);
            }
        }
    }
}

// GEMM2 (gathered, split-K=KSPLIT, no atomics):
// Y[ks][off[e]+i][h] = (Ag_e @ W2_e)[i][h] over k in [ks*KS,(ks+1)*KS)
__global__ __launch_bounds__(256, 4)
void gemm2_kernel(const __hip_bfloat16* __restrict__ Ag,
                  const __hip_bfloat16* __restrict__ W2t,
                  const int* __restrict__ cnt, const int* __restrict__ off,
                  __hip_bfloat16* __restrict__ Y) {
    const int e  = blockIdx.z >> 2, kh = blockIdx.z & 3;
    const int ce = cnt[e];
    const int m0 = blockIdx.y * BM;
    if (m0 >= ce) return;
    const int n0 = blockIdx.x * BN;   // over H
    const int oe = off[e];
    __shared__ __align__(16) __hip_bfloat16 Bs[BN * BK];
    const int tid = threadIdx.x, lane = tid & 63, wave = tid >> 6;
    const int wm = (wave >> 1) * 64, wn = (wave & 1) * 64;
    const int lr  = lane >> 3;
    const int lcg = ((lane & 7) ^ lr) * 8;
    const int mr  = lane & 15;
    const int kq8 = (lane >> 4) * 8;
    // A rows are contiguous in the gathered buffer (padded rows are valid dup data)
    const __hip_bfloat16* Abase = Ag + (size_t)(oe + m0 + wm + mr) * F_ + kh * KS;
    const __hip_bfloat16* Bbase = W2t + (size_t)e * F_ + kh * KS;

    f32x4 acc[4][4];
#pragma unroll
    for (int mi = 0; mi < 4; mi++)
#pragma unroll
        for (int ni = 0; ni < 4; ni++) acc[mi][ni] = (f32x4){0.f, 0.f, 0.f, 0.f};

    for (int k0 = 0; k0 < KS; k0 += BK) {
#pragma unroll
        for (int j = 0; j < 4; j++) {
            const int i = wave * 4 + j;
            async_copy16(Bbase + (size_t)(n0 + i * 8 + lr) * EF_ + (k0 + lcg),
                         (char*)Bs + i * 1024);
        }
        short8 a0[4], a1[4];
#pragma unroll
        for (int mi = 0; mi < 4; mi++)
            a0[mi] = *(const short8*)&Abase[(size_t)(mi * 16) * F_ + k0 + kq8];
#pragma unroll
        for (int mi = 0; mi < 4; mi++)
            a1[mi] = *(const short8*)&Abase[(size_t)(mi * 16) * F_ + k0 + 32 + kq8];
        __syncthreads();
#pragma unroll
        for (int kt = 0; kt < 2; kt++) {
            const int kq = kt * 4 + (lane >> 4);
            const int sw = mr & 7;
            short8 bF[4];
#pragma unroll
            for (int ni = 0; ni < 4; ni++)
                bF[ni] = *(const short8*)&Bs[(wn + ni * 16 + mr) * BK + ((kq ^ sw) << 3)];
#pragma unroll
            for (int mi = 0; mi < 4; mi++)
#pragma unroll
                for (int ni = 0; ni < 4; ni++)
                    acc[mi][ni] = __builtin_amdgcn_mfma_f32_16x16x32_bf16(
                        kt ? a1[mi] : a0[mi], bF[ni], acc[mi][ni], 0, 0, 0);
        }
        __syncthreads();
    }
    const int rq = (lane >> 4) * 4, cq = lane & 15;
    __hip_bfloat16* Yk = Y + (size_t)kh * ROWCAP * H_ + (size_t)(oe + m0) * H_;
#pragma unroll
    for (int mi = 0; mi < 4; mi++)
#pragma unroll
        for (int reg = 0; reg < 4; reg++) {
            const int rl = wm + mi * 16 + rq + reg;
#pragma unroll
            for (int ni = 0; ni < 4; ni++) {
                const int col = n0 + wn + ni * 16 + cq;
                Yk[(size_t)rl * H_ + col] = __float2bfloat16(acc[mi][ni][reg]);
            }
        }
}

// out[t][h] = res[t][h] + sum_{e routed} sum_{ks} Y[ks][off[e]+slot[t][e]][h]
__global__ __launch_bounds__(256)
void combine_kernel(const float* __restrict__ res, const float* __restrict__ probs,
                    const int* __restrict__ off, const int* __restrict__ slot,
                    const __hip_bfloat16* __restrict__ Y, float* __restrict__ out) {
    const int idx = blockIdx.x * 256 + threadIdx.x;   // T_*(H_/4) threads
    const int t  = idx >> 8;
    const int hc = (idx & 255) * 4;
    const float4 r = ((const float4*)res)[idx];
    float s0 = r.x, s1 = r.y, s2 = r.z, s3 = r.w;
#pragma unroll
    for (int e = 0; e < E_; e++) {
        if (probs[(size_t)t * E_ + e] > 0.0f) {
            const int row = off[e] + slot[(size_t)t * E_ + e];
#pragma unroll
            for (int ks = 0; ks < KSPLIT; ks++) {
                const ushort4 y = *(const ushort4*)&Y[((size_t)ks * ROWCAP + row) * H_ + hc];
                s0 += bf2f(y.x); s1 += bf2f(y.y); s2 += bf2f(y.z); s3 += bf2f(y.w);
            }
        }
    }
    ((float4*)out)[idx] = make_float4(s0, s1, s2, s3);
}

extern "C" void kernel_launch(void* const* d_in, const int* in_sizes, int n_in,
                              void* d_out, int out_size, void* d_ws, size_t ws_size,
                              hipStream_t stream) {
    const float* x     = (const float*)d_in[0];
    const float* res   = (const float*)d_in[1];
    const float* probs = (const float*)d_in[2];
    const float* w1    = (const float*)d_in[4];
    const float* w2    = (const float*)d_in[5];
    float* out = (float*)d_out;

    char* ws = (char*)d_ws;
    // Y (36 MiB) ALIASES Xb+W1t: both are dead after gemm1, and gemm2 (writes Y)
    // runs after gemm1 in stream order. Every call rewrites Xb/W1t before gemm1.
    __hip_bfloat16* Y   = (__hip_bfloat16*)(ws);                 // 36 MiB (KSPLIT slices)
    __hip_bfloat16* Xb  = (__hip_bfloat16*)(ws);                 //  4 MiB (dead after gemm1)
    __hip_bfloat16* W1t = (__hip_bfloat16*)(ws + (4ull  << 20)); // 32 MiB (dead after gemm1)
    __hip_bfloat16* W2t = (__hip_bfloat16*)(ws + (36ull << 20)); // 32 MiB
    __hip_bfloat16* Ag  = (__hip_bfloat16*)(ws + (68ull << 20)); // 36 MiB
    char* meta = ws + (104ull << 20);
    int* cnt  = (int*)meta;                       // 4 ints
    int* off  = (int*)(meta + 64);                // 5 ints
    int* list = (int*)(meta + 256);               // E*T ints = 32 KB
    int* slot = (int*)(meta + 256 + 4 * T_ * 4);  // T*E ints = 32 KB

    // 4 graph nodes: prep, gemm1, gemm2, combine.
    trans_kernel<<<dim3(64, 16, 2 * E_ + 1), dim3(256), 0, stream>>>(
        w1, w2, x, probs, W1t, W2t, Xb, cnt, off, list, slot);
    gemm1_kernel<<<dim3(F_ / BN, T_ / BM, E_), dim3(256), 0, stream>>>(
        Xb, W1t, probs, cnt, off, list, Ag);
    gemm2_kernel<<<dim3(H_ / BN, T_ / BM, KSPLIT * E_), dim3(256), 0, stream>>>(
        Ag, W2t, cnt, off, Y);
    combine_kernel<<<dim3(T_ * (H_ / 4) / 256), dim3(256), 0, stream>>>(
        res, probs, off, slot, Y, out);
}

// Round 9
// 302.678 us; speedup vs baseline: 1.3383x; 1.3383x over previous
//
#include <hip/hip_runtime.h>
#include <hip/hip_bf16.h>
#include <math.h>

// Problem constants (S=1024, B=2 -> T=2048)
#define T_  2048
#define H_  1024
#define F_  4096
#define E_  4
#define EF_ (E_*F_)
#define ROWCAP 4608   // sum_e ceil(cnt_e/128)*128 <= 4096 + 4*127 = 4604
#define KSPLIT 4      // gemm2 split-K slices
#define KS (F_/KSPLIT)

typedef __attribute__((ext_vector_type(8)))  short short8;   // 8 bf16 = 4 VGPRs
typedef __attribute__((ext_vector_type(16))) float f32x16;   // MFMA 32x32 accumulator

#define BM 128
#define BN 128
#define BK 64

__device__ __forceinline__ void async_copy16(const void* g, void* l) {
    __builtin_amdgcn_global_load_lds(
        (const __attribute__((address_space(1))) void*)g,
        (__attribute__((address_space(3))) void*)l, 16, 0, 0);
}

__device__ __forceinline__ float bf2f(unsigned short u) {
    return __uint_as_float(((unsigned)u) << 16);
}
__device__ __forceinline__ short f2bf_bits(float f) {
    __hip_bfloat16 b = __float2bfloat16(f);
    return *(short*)&b;
}

// ONE prep kernel, grid (64,16,9):
//   z<4 : W1 expert z   [H][F] fp32 -> w1t[e][f][h] bf16 (64x64 LDS transpose)
//   4<=z<8 : W2 expert z-4 [F][H] fp32 -> w2t[h][e*F+f] bf16
//   z==8: X copy-convert fp32->bf16; block (0,0,8) also builds routing lists.
__global__ __launch_bounds__(256)
void trans_kernel(const float* __restrict__ w1, const float* __restrict__ w2,
                  const float* __restrict__ x,  const float* __restrict__ probs,
                  __hip_bfloat16* __restrict__ w1t, __hip_bfloat16* __restrict__ w2t,
                  __hip_bfloat16* __restrict__ xb,
                  int* __restrict__ cnt_g, int* __restrict__ off_g,
                  int* __restrict__ list, int* __restrict__ slot) {
    const int z = blockIdx.z;
    const int t = threadIdx.x;

    if (z == 2 * E_) {
        // ---- X convert path ----
        const int bid = blockIdx.y * 64 + blockIdx.x;          // 0..1023
        const size_t base = ((size_t)bid * 256 + t) * 8;       // 8 elems/thread
        const float4 v0 = *(const float4*)&x[base];
        const float4 v1 = *(const float4*)&x[base + 4];
        short8 pk;
        pk[0] = f2bf_bits(v0.x); pk[1] = f2bf_bits(v0.y);
        pk[2] = f2bf_bits(v0.z); pk[3] = f2bf_bits(v0.w);
        pk[4] = f2bf_bits(v1.x); pk[5] = f2bf_bits(v1.y);
        pk[6] = f2bf_bits(v1.z); pk[7] = f2bf_bits(v1.w);
        *(short8*)&((short*)xb)[base] = pk;

        // ---- routing (single designated block) ----
        if (blockIdx.x == 0 && blockIdx.y == 0) {
            __shared__ int lcnt[E_];
            if (t < E_) lcnt[t] = 0;
            __syncthreads();
            const int lane = t & 63;
            const unsigned long long below = ((lane == 63) ? ~0ull : ((1ull << (lane + 1)) - 1)) >> 1;
#pragma unroll
            for (int i = 0; i < T_ / 256; i++) {
                const int tok = i * 256 + t;
                const float4 p = *(const float4*)&probs[(size_t)tok * E_];
                const float pv[4] = {p.x, p.y, p.z, p.w};
#pragma unroll
                for (int e = 0; e < E_; e++) {
                    const bool r = pv[e] > 0.0f;
                    const unsigned long long mask = __ballot(r);
                    int base_pos = 0;
                    if (lane == 0) base_pos = atomicAdd(&lcnt[e], __popcll(mask));
                    base_pos = __shfl(base_pos, 0);
                    const int pos = base_pos + (int)__popcll(mask & below);
                    if (r) { list[e * T_ + pos] = tok; slot[tok * E_ + e] = pos; }
                }
            }
            __syncthreads();
            if (t == 0) {
                int acc = 0;
#pragma unroll
                for (int e = 0; e < E_; e++) {
                    off_g[e] = acc; cnt_g[e] = lcnt[e];
                    acc += (lcnt[e] + 127) & ~127;
                }
                off_g[E_] = acc;
            }
        }
        return;
    }

    // ---- weight transpose paths (verified R6) ----
    __shared__ float tile[64 * 69 + 4];   // tile[c][r] at c*69 + r
    const float* src;
    __hip_bfloat16* dst;
    int r0, c0, C, dstStride;
    if (z < E_) {
        src = w1 + (size_t)z * H_ * F_;
        dst = w1t + (size_t)z * F_ * H_;
        C = F_; dstStride = H_;
        r0 = blockIdx.y * 64;   // over H
        c0 = blockIdx.x * 64;   // over F
    } else {
        const int e = z - E_;
        src = w2 + (size_t)e * F_ * H_;
        dst = w2t + (size_t)e * F_;     // element (r=f,c=h) -> dst[c*EF_ + r]
        C = H_; dstStride = EF_;
        r0 = blockIdx.x * 64;   // over F
        c0 = blockIdx.y * 64;   // over H
    }
    const int cl = (t & 15) * 4;
#pragma unroll
    for (int p = 0; p < 4; p++) {
        const int rl = (t >> 4) + 16 * p;
        const float4 v = *(const float4*)&src[(size_t)(r0 + rl) * C + (c0 + cl)];
        tile[(cl + 0) * 69 + rl] = v.x;
        tile[(cl + 1) * 69 + rl] = v.y;
        tile[(cl + 2) * 69 + rl] = v.z;
        tile[(cl + 3) * 69 + rl] = v.w;
    }
    __syncthreads();
    const int orow = (t & 7) * 8;
#pragma unroll
    for (int q = 0; q < 2; q++) {
        const int oc = (t >> 3) + 32 * q;
        short8 pk;
#pragma unroll
        for (int j = 0; j < 8; j++)
            pk[j] = f2bf_bits(tile[oc * 69 + orow + j]);
        *(short8*)&((short*)dst)[(size_t)(c0 + oc) * dstStride + r0 + orow] = pk;
    }
}

// LDS swizzle: row r chunk c stored at c ^ (r&7); staging fetches the permuted global
// chunk per lane; readers XOR. Conflict-free (verified R2: 2.5e7 -> 0).
// MFMA shape: 32x32x16 bf16 (half the instructions of 16x16x32 for the same FLOPs).
// A/B frag: row = base + (lane&31), k-chunk = lane>>5 (widened from the verified 16x16
// pattern). C/D: col = lane&31, row = (reg&3) + 8*(reg>>2) + 4*(lane>>5)  [m74/m101].

// GEMM1 (gathered): Ag[off[e]+i][f] = bf16( p * gelu( (X[list[e][i]] @ W1_e)[f] ) )
__global__ __launch_bounds__(256)
void gemm1_kernel(const __hip_bfloat16* __restrict__ Xb,
                  const __hip_bfloat16* __restrict__ W1t,
                  const float* __restrict__ probs,
                  const int* __restrict__ cnt, const int* __restrict__ off,
                  const int* __restrict__ list,
                  __hip_bfloat16* __restrict__ Ag) {
    const int e  = blockIdx.z;
    const int ce = cnt[e];
    const int m0 = blockIdx.y * BM;
    if (m0 >= ce) return;
    const int n0 = blockIdx.x * BN;   // over F
    const __hip_bfloat16* Bt = W1t + (size_t)e * F_ * H_;
    __shared__ __align__(16) __hip_bfloat16 As[BM * BK];
    __shared__ __align__(16) __hip_bfloat16 Bs[BN * BK];
    const int tid = threadIdx.x, lane = tid & 63, wave = tid >> 6;
    const int wm = (wave >> 1) * 64, wn = (wave & 1) * 64;
    const int lr  = lane >> 3;
    const int lcg = ((lane & 7) ^ lr) * 8;

    int tokA[4];
#pragma unroll
    for (int j = 0; j < 4; j++) {
        int idx = m0 + (wave * 4 + j) * 8 + lr;
        if (idx >= ce) idx = ce - 1;          // clamp: dup row, store discarded below
        tokA[j] = list[e * T_ + idx];
    }

    f32x16 acc[2][2];
#pragma unroll
    for (int mi = 0; mi < 2; mi++)
#pragma unroll
        for (int ni = 0; ni < 2; ni++)
#pragma unroll
            for (int r = 0; r < 16; r++) acc[mi][ni][r] = 0.f;

    const int l31 = lane & 31, kh5 = lane >> 5, sw = lane & 7;

    for (int k0 = 0; k0 < H_; k0 += BK) {
#pragma unroll
        for (int j = 0; j < 4; j++) {
            const int i = wave * 4 + j;
            const int r = i * 8 + lr;
            async_copy16(Xb + (size_t)tokA[j] * H_ + (k0 + lcg), (char*)As + i * 1024);
            async_copy16(Bt + (size_t)(n0 + r) * H_ + (k0 + lcg), (char*)Bs + i * 1024);
        }
        __syncthreads();
#pragma unroll
        for (int ks = 0; ks < 4; ks++) {
            const int kq = ks * 2 + kh5;          // 16B-chunk index, 0..7
            short8 aF[2], bF[2];
#pragma unroll
            for (int mi = 0; mi < 2; mi++)
                aF[mi] = *(const short8*)&As[(wm + mi * 32 + l31) * BK + ((kq ^ sw) << 3)];
#pragma unroll
            for (int ni = 0; ni < 2; ni++)
                bF[ni] = *(const short8*)&Bs[(wn + ni * 32 + l31) * BK + ((kq ^ sw) << 3)];
#pragma unroll
            for (int mi = 0; mi < 2; mi++)
#pragma unroll
                for (int ni = 0; ni < 2; ni++)
                    acc[mi][ni] = __builtin_amdgcn_mfma_f32_32x32x16_bf16(
                        aF[mi], bF[ni], acc[mi][ni], 0, 0, 0);
        }
        __syncthreads();
    }
    // C/D: col = lane&31, row = (reg&3) + 8*(reg>>2) + 4*(lane>>5)
    const int obase = off[e] + m0;
#pragma unroll
    for (int mi = 0; mi < 2; mi++) {
#pragma unroll
        for (int reg = 0; reg < 16; reg++) {
            const int r32 = (reg & 3) + 8 * (reg >> 2) + 4 * kh5;
            const int rl = wm + mi * 32 + r32;
            int ci = m0 + rl; if (ci >= ce) ci = ce - 1;
            const int tok = list[e * T_ + ci];
            const float pv = probs[(size_t)tok * E_ + e];
#pragma unroll
            for (int ni = 0; ni < 2; ni++) {
                const int col = n0 + wn + ni * 32 + l31;
                const float v = acc[mi][ni][reg];
                // tanh-gelu via sigmoid: 0.5(1+tanh(u)) = sigma(2u); dev vs erf-gelu ~3e-3
                const float u = 0.7978845608028654f * v * (1.0f + 0.044715f * v * v);
                const float g = v / (1.0f + __expf(-2.0f * u));
                Ag[(size_t)(obase + rl) * F_ + col] = __float2bfloat16(g * pv);
            }
        }
    }
}

// GEMM2 (gathered, split-K=KSPLIT, no atomics):
// Y[ks][off[e]+i][h] = (Ag_e @ W2_e)[i][h] over k in [ks*KS,(ks+1)*KS)
__global__ __launch_bounds__(256)
void gemm2_kernel(const __hip_bfloat16* __restrict__ Ag,
                  const __hip_bfloat16* __restrict__ W2t,
                  const int* __restrict__ cnt, const int* __restrict__ off,
                  __hip_bfloat16* __restrict__ Y) {
    const int e  = blockIdx.z >> 2, kh = blockIdx.z & 3;
    const int ce = cnt[e];
    const int m0 = blockIdx.y * BM;
    if (m0 >= ce) return;
    const int n0 = blockIdx.x * BN;   // over H
    const int oe = off[e];
    __shared__ __align__(16) __hip_bfloat16 As[BM * BK];
    __shared__ __align__(16) __hip_bfloat16 Bs[BN * BK];
    const int tid = threadIdx.x, lane = tid & 63, wave = tid >> 6;
    const int wm = (wave >> 1) * 64, wn = (wave & 1) * 64;
    const int lr  = lane >> 3;
    const int lcg = ((lane & 7) ^ lr) * 8;
    const __hip_bfloat16* Abase = Ag + (size_t)oe * F_ + kh * KS;
    const __hip_bfloat16* Bbase = W2t + (size_t)e * F_ + kh * KS;

    f32x16 acc[2][2];
#pragma unroll
    for (int mi = 0; mi < 2; mi++)
#pragma unroll
        for (int ni = 0; ni < 2; ni++)
#pragma unroll
            for (int r = 0; r < 16; r++) acc[mi][ni][r] = 0.f;

    const int l31 = lane & 31, kh5 = lane >> 5, sw = lane & 7;

    for (int k0 = 0; k0 < KS; k0 += BK) {
#pragma unroll
        for (int j = 0; j < 4; j++) {
            const int i = wave * 4 + j;
            const int r = i * 8 + lr;
            async_copy16(Abase + (size_t)(m0 + r) * F_ + (k0 + lcg), (char*)As + i * 1024);
            async_copy16(Bbase + (size_t)(n0 + r) * EF_ + (k0 + lcg), (char*)Bs + i * 1024);
        }
        __syncthreads();
#pragma unroll
        for (int ks = 0; ks < 4; ks++) {
            const int kq = ks * 2 + kh5;
            short8 aF[2], bF[2];
#pragma unroll
            for (int mi = 0; mi < 2; mi++)
                aF[mi] = *(const short8*)&As[(wm + mi * 32 + l31) * BK + ((kq ^ sw) << 3)];
#pragma unroll
            for (int ni = 0; ni < 2; ni++)
                bF[ni] = *(const short8*)&Bs[(wn + ni * 32 + l31) * BK + ((kq ^ sw) << 3)];
#pragma unroll
            for (int mi = 0; mi < 2; mi++)
#pragma unroll
                for (int ni = 0; ni < 2; ni++)
                    acc[mi][ni] = __builtin_amdgcn_mfma_f32_32x32x16_bf16(
                        aF[mi], bF[ni], acc[mi][ni], 0, 0, 0);
        }
        __syncthreads();
    }
    __hip_bfloat16* Yk = Y + (size_t)kh * ROWCAP * H_ + (size_t)(oe + m0) * H_;
#pragma unroll
    for (int mi = 0; mi < 2; mi++)
#pragma unroll
        for (int reg = 0; reg < 16; reg++) {
            const int r32 = (reg & 3) + 8 * (reg >> 2) + 4 * kh5;
            const int rl = wm + mi * 32 + r32;
#pragma unroll
            for (int ni = 0; ni < 2; ni++) {
                const int col = n0 + wn + ni * 32 + l31;
                Yk[(size_t)rl * H_ + col] = __float2bfloat16(acc[mi][ni][reg]);
            }
        }
}

// out[t][h] = res[t][h] + sum_{e routed} sum_{ks} Y[ks][off[e]+slot[t][e]][h]
__global__ __launch_bounds__(256)
void combine_kernel(const float* __restrict__ res, const float* __restrict__ probs,
                    const int* __restrict__ off, const int* __restrict__ slot,
                    const __hip_bfloat16* __restrict__ Y, float* __restrict__ out) {
    const int idx = blockIdx.x * 256 + threadIdx.x;   // T_*(H_/4) threads
    const int t  = idx >> 8;
    const int hc = (idx & 255) * 4;
    const float4 r = ((const float4*)res)[idx];
    float s0 = r.x, s1 = r.y, s2 = r.z, s3 = r.w;
#pragma unroll
    for (int e = 0; e < E_; e++) {
        if (probs[(size_t)t * E_ + e] > 0.0f) {
            const int row = off[e] + slot[(size_t)t * E_ + e];
#pragma unroll
            for (int ks = 0; ks < KSPLIT; ks++) {
                const ushort4 y = *(const ushort4*)&Y[((size_t)ks * ROWCAP + row) * H_ + hc];
                s0 += bf2f(y.x); s1 += bf2f(y.y); s2 += bf2f(y.z); s3 += bf2f(y.w);
            }
        }
    }
    ((float4*)out)[idx] = make_float4(s0, s1, s2, s3);
}

extern "C" void kernel_launch(void* const* d_in, const int* in_sizes, int n_in,
                              void* d_out, int out_size, void* d_ws, size_t ws_size,
                              hipStream_t stream) {
    const float* x     = (const float*)d_in[0];
    const float* res   = (const float*)d_in[1];
    const float* probs = (const float*)d_in[2];
    const float* w1    = (const float*)d_in[4];
    const float* w2    = (const float*)d_in[5];
    float* out = (float*)d_out;

    char* ws = (char*)d_ws;
    // Y (36 MiB) ALIASES Xb+W1t: both are dead after gemm1, and gemm2 (writes Y)
    // runs after gemm1 in stream order. Every call rewrites Xb/W1t before gemm1.
    __hip_bfloat16* Y   = (__hip_bfloat16*)(ws);                 // 36 MiB (KSPLIT slices)
    __hip_bfloat16* Xb  = (__hip_bfloat16*)(ws);                 //  4 MiB (dead after gemm1)
    __hip_bfloat16* W1t = (__hip_bfloat16*)(ws + (4ull  << 20)); // 32 MiB (dead after gemm1)
    __hip_bfloat16* W2t = (__hip_bfloat16*)(ws + (36ull << 20)); // 32 MiB
    __hip_bfloat16* Ag  = (__hip_bfloat16*)(ws + (68ull << 20)); // 36 MiB
    char* meta = ws + (104ull << 20);
    int* cnt  = (int*)meta;                       // 4 ints
    int* off  = (int*)(meta + 64);                // 5 ints
    int* list = (int*)(meta + 256);               // E*T ints = 32 KB
    int* slot = (int*)(meta + 256 + 4 * T_ * 4);  // T*E ints = 32 KB

    // 4 graph nodes: prep, gemm1, gemm2, combine.
    trans_kernel<<<dim3(64, 16, 2 * E_ + 1), dim3(256), 0, stream>>>(
        w1, w2, x, probs, W1t, W2t, Xb, cnt, off, list, slot);
    gemm1_kernel<<<dim3(F_ / BN, T_ / BM, E_), dim3(256), 0, stream>>>(
        Xb, W1t, probs, cnt, off, list, Ag);
    gemm2_kernel<<<dim3(H_ / BN, T_ / BM, KSPLIT * E_), dim3(256), 0, stream>>>(
        Ag, W2t, cnt, off, Y);
    combine_kernel<<<dim3(T_ * (H_ / 4) / 256), dim3(256), 0, stream>>>(
        res, probs, off, slot, Y, out);
}